// Round 4
// baseline (313.974 us; speedup 1.0000x reference)
//
#include <hip/hip_runtime.h>
#include <hip/hip_cooperative_groups.h>

#define DDIM 256
#define WPB 4      // waves per block (256 threads)
#define HALVES 2   // waves per entity; each wave owns DDIM/HALVES columns

namespace cg = cooperative_groups;

// ---------------- fused cooperative kernel ----------------
__global__ __launch_bounds__(256, 8)
void fused_kernel(const float* __restrict__ enc,
                  const int* __restrict__ info,
                  int* __restrict__ cursor,   // [E]
                  int* __restrict__ bucket,   // [E][M]
                  float* __restrict__ out,    // [E][D]
                  int M, int E) {
    cg::grid_group grid = cg::this_grid();
    int tid = blockIdx.x * blockDim.x + threadIdx.x;
    int nthreads = gridDim.x * blockDim.x;

    // Phase 0: zero cursors (graph replays leave stale values).
    for (int e = tid; e < E; e += nthreads) cursor[e] = 0;
    grid.sync();

    // Phase 1: scatter mention ids into per-entity buckets.
    for (int m = tid; m < M; m += nthreads) {
        int eid = info[(size_t)m * 4];
        int pos = atomicAdd(cursor + eid, 1);
        bucket[(size_t)eid * M + pos] = m;
    }
    grid.sync();

    // Phase 2: per-entity gather+mean. 2 waves per entity (column halves).
    int lane = threadIdx.x & 63;
    int waveInGrid = tid >> 6;
    int totalWaves = nthreads >> 6;
    const int COLS2 = DDIM / 2;            // row length in float2
    const int HW    = DDIM / (2 * HALVES); // float2 elems per wave (=64)

    for (int gw = waveInGrid; gw < E * HALVES; gw += totalWaves) {
        int e    = gw / HALVES;
        int half = gw % HALVES;

        int cnt = cursor[e];
        const int* bk = bucket + (size_t)e * M;

        float2 eacc = make_float2(0.f, 0.f);
        for (int j0 = 0; j0 < cnt; j0 += 64) {
            int nj = min(cnt - j0, 64);
            int mystart = 0, mylen = 0;
            if (lane < nj) {
                int m = bk[j0 + lane];
                int4 r = reinterpret_cast<const int4*>(info)[m];
                mystart = r.z;
                mylen   = r.w - r.z;
            }
            for (int j = 0; j < nj; ++j) {
                int start = __shfl(mystart, j);
                int len   = __shfl(mylen, j);
                const float2* base = reinterpret_cast<const float2*>(enc)
                                     + (size_t)start * COLS2 + half * HW + lane;
                float2 macc = make_float2(0.f, 0.f);
                #pragma unroll 4
                for (int i = 0; i < len; ++i) {
                    float2 v = base[(size_t)i * COLS2];
                    macc.x += v.x; macc.y += v.y;
                }
                float inv = (len > 0) ? 1.0f / (float)len : 0.0f;
                eacc.x += macc.x * inv;
                eacc.y += macc.y * inv;
            }
        }
        float invc = 1.0f / fmaxf((float)cnt, 1.0f);
        reinterpret_cast<float2*>(out)[(size_t)e * COLS2 + half * HW + lane] =
            make_float2(eacc.x * invc, eacc.y * invc);
    }
}

// ---------------- non-coop fallback kernels ----------------
__global__ void scatter_kernel(const int* __restrict__ info,
                               int* __restrict__ cursor,
                               int* __restrict__ bucket, int M) {
    int m = blockIdx.x * blockDim.x + threadIdx.x;
    if (m >= M) return;
    int eid = info[(size_t)m * 4];
    int pos = atomicAdd(cursor + eid, 1);
    bucket[(size_t)eid * M + pos] = m;
}

__global__ void entity_kernel(const float* __restrict__ enc,
                              const int* __restrict__ info,
                              const int* __restrict__ cursor,
                              const int* __restrict__ bucket,
                              float* __restrict__ out, int M, int E) {
    int gw = blockIdx.x * WPB + (threadIdx.x >> 6);
    int e = gw / HALVES, half = gw % HALVES;
    if (e >= E) return;
    int lane = threadIdx.x & 63;
    int cnt = cursor[e];
    const int* bk = bucket + (size_t)e * M;
    const int COLS2 = DDIM / 2;
    const int HW    = DDIM / (2 * HALVES);
    float2 eacc = make_float2(0.f, 0.f);
    for (int j0 = 0; j0 < cnt; j0 += 64) {
        int nj = min(cnt - j0, 64);
        int mystart = 0, mylen = 0;
        if (lane < nj) {
            int m = bk[j0 + lane];
            int4 r = reinterpret_cast<const int4*>(info)[m];
            mystart = r.z; mylen = r.w - r.z;
        }
        for (int j = 0; j < nj; ++j) {
            int start = __shfl(mystart, j);
            int len   = __shfl(mylen, j);
            const float2* base = reinterpret_cast<const float2*>(enc)
                                 + (size_t)start * COLS2 + half * HW + lane;
            float2 macc = make_float2(0.f, 0.f);
            #pragma unroll 4
            for (int i = 0; i < len; ++i) {
                float2 v = base[(size_t)i * COLS2];
                macc.x += v.x; macc.y += v.y;
            }
            float inv = (len > 0) ? 1.0f / (float)len : 0.0f;
            eacc.x += macc.x * inv;
            eacc.y += macc.y * inv;
        }
    }
    float invc = 1.0f / fmaxf((float)cnt, 1.0f);
    reinterpret_cast<float2*>(out)[(size_t)e * COLS2 + half * HW + lane] =
        make_float2(eacc.x * invc, eacc.y * invc);
}

// ---------------- Path B (ws too small): atomic version ----------------
__global__ void mention_accum_kernel(const float* __restrict__ enc,
                                     const int* __restrict__ info,
                                     float* __restrict__ ent_sum,
                                     float* __restrict__ cnt, int M) {
    int wave = blockIdx.x * WPB + (threadIdx.x >> 6);
    if (wave >= M) return;
    int lane = threadIdx.x & 63;
    const int* r = info + (size_t)wave * 4;
    int eid = r[0], start = r[2], len = r[3] - r[2];
    if (len <= 0) {
        if (lane == 0) atomicAdd(cnt + eid, 1.0f);
        return;
    }
    const float4* base = reinterpret_cast<const float4*>(enc)
                         + (size_t)start * (DDIM / 4) + lane;
    float4 acc = make_float4(0.f, 0.f, 0.f, 0.f);
    for (int i = 0; i < len; ++i) {
        float4 v = base[(size_t)i * (DDIM / 4)];
        acc.x += v.x; acc.y += v.y; acc.z += v.z; acc.w += v.w;
    }
    float inv = 1.0f / (float)len;
    float* dst = ent_sum + (size_t)eid * DDIM + lane * 4;
    atomicAdd(dst + 0, acc.x * inv);
    atomicAdd(dst + 1, acc.y * inv);
    atomicAdd(dst + 2, acc.z * inv);
    atomicAdd(dst + 3, acc.w * inv);
    if (lane == 0) atomicAdd(cnt + eid, 1.0f);
}

__global__ void finalize_kernel(float* __restrict__ out,
                                const float* __restrict__ cnt, int n) {
    int t = blockIdx.x * blockDim.x + threadIdx.x;
    if (t >= n) return;
    out[t] = out[t] / fmaxf(cnt[t >> 8], 1.0f);
}

extern "C" void kernel_launch(void* const* d_in, const int* in_sizes, int n_in,
                              void* d_out, int out_size, void* d_ws, size_t ws_size,
                              hipStream_t stream) {
    const float* enc  = (const float*)d_in[0];
    const int*   info = (const int*)d_in[1];   // int64 in source, but JAX x64 off -> int32

    int M = in_sizes[1] / 4;
    int E = out_size / DDIM;
    float* out = (float*)d_out;

    size_t cursor_bytes = ((size_t)E * sizeof(int) + 255) & ~(size_t)255;
    size_t need = cursor_bytes + (size_t)E * (size_t)M * sizeof(int);

    if (ws_size >= need) {
        int* cursor = (int*)d_ws;
        int* bucket = (int*)((char*)d_ws + cursor_bytes);

        // Grid sized for co-residency: 8 blocks/CU x 256 CU = 2048 max.
        int wanted = (E * HALVES + WPB - 1) / WPB;
        int blocks = wanted < 2048 ? wanted : 2048;

        void* args[] = {(void*)&enc, (void*)&info, (void*)&cursor,
                        (void*)&bucket, (void*)&out, (void*)&M, (void*)&E};
        hipError_t err = hipLaunchCooperativeKernel(
            (const void*)fused_kernel, dim3(blocks), dim3(64 * WPB),
            args, 0, stream);
        if (err != hipSuccess) {
            // non-cooperative 3-dispatch fallback
            hipMemsetAsync(cursor, 0, (size_t)E * sizeof(int), stream);
            scatter_kernel<<<(M + 255) / 256, 256, 0, stream>>>(info, cursor, bucket, M);
            int b2 = (E * HALVES + WPB - 1) / WPB;
            entity_kernel<<<b2, 64 * WPB, 0, stream>>>(enc, info, cursor, bucket, out, M, E);
        }
    } else {
        float* cnt = (float*)d_ws;
        hipMemsetAsync(d_out, 0, (size_t)out_size * sizeof(float), stream);
        hipMemsetAsync(cnt, 0, (size_t)E * sizeof(float), stream);
        int blocks = (M + WPB - 1) / WPB;
        mention_accum_kernel<<<blocks, 64 * WPB, 0, stream>>>(enc, info, out, cnt, M);
        finalize_kernel<<<(out_size + 255) / 256, 256, 0, stream>>>(out, cnt, out_size);
    }
}

// Round 5
// 39.743 us; speedup vs baseline: 7.9002x; 7.9002x over previous
//
#include <hip/hip_runtime.h>

#define DDIM 256
#define WPB 4      // waves per block (256 threads)
#define HALVES 2   // waves per entity; each wave owns DDIM/HALVES columns

// ---------- Path A: group-by-entity, zero output atomics ----------

// Scatter packed (start,len) headers into per-entity buckets.
// info read is a coalesced int4 per mention; M (=20000) int atomics total.
__global__ void scatter_kernel(const int* __restrict__ info,
                               int* __restrict__ cursor,     // [E], pre-zeroed
                               int2* __restrict__ bucket,    // [E][strideI2]
                               int M, int strideI2) {
    int m = blockIdx.x * blockDim.x + threadIdx.x;
    if (m >= M) return;
    int4 r = reinterpret_cast<const int4*>(info)[m];  // [eid, etype, start, end]
    int pos = atomicAdd(cursor + r.x, 1);
    bucket[(size_t)r.x * strideI2 + pos] = make_int2(r.z, r.w - r.z);
}

// 2 waves per entity (column halves). Headers fetched in parallel across
// lanes then shfl-broadcast; row gathers stream with no dependent chain.
__global__ void entity_kernel(const float* __restrict__ enc,
                              const int* __restrict__ cursor,   // counts
                              const int2* __restrict__ bucket,  // packed headers
                              float* __restrict__ out,
                              int strideI2, int E) {
    int gw = blockIdx.x * WPB + (threadIdx.x >> 6);
    int e    = gw >> 1;          // HALVES == 2
    int half = gw & 1;
    if (e >= E) return;
    int lane = threadIdx.x & 63;

    int cnt = cursor[e];
    const int2* bk = bucket + (size_t)e * strideI2;

    const int COLS2 = DDIM / 2;            // row length in float2
    const int HW    = DDIM / (2 * HALVES); // float2 elems per wave (=64)

    float2 eacc = make_float2(0.f, 0.f);
    for (int j0 = 0; j0 < cnt; j0 += 64) {
        int nj = min(cnt - j0, 64);
        int mystart = 0, mylen = 0;
        if (lane < nj) {
            int2 h = bk[j0 + lane];
            mystart = h.x;
            mylen   = h.y;
        }
        for (int j = 0; j < nj; ++j) {
            int start = __shfl(mystart, j);
            int len   = __shfl(mylen, j);
            const float2* base = reinterpret_cast<const float2*>(enc)
                                 + (size_t)start * COLS2 + half * HW + lane;
            float2 macc = make_float2(0.f, 0.f);
            #pragma unroll 4
            for (int i = 0; i < len; ++i) {
                float2 v = base[(size_t)i * COLS2];
                macc.x += v.x; macc.y += v.y;
            }
            float inv = (len > 0) ? 1.0f / (float)len : 0.0f;
            eacc.x += macc.x * inv;
            eacc.y += macc.y * inv;
        }
    }
    float invc = 1.0f / fmaxf((float)cnt, 1.0f);
    reinterpret_cast<float2*>(out)[(size_t)e * COLS2 + half * HW + lane] =
        make_float2(eacc.x * invc, eacc.y * invc);
}

// ---------- Path B (fallback if ws too small): atomic version ----------

__global__ void mention_accum_kernel(const float* __restrict__ enc,
                                     const int* __restrict__ info,
                                     float* __restrict__ ent_sum,
                                     float* __restrict__ cnt, int M) {
    int wave = blockIdx.x * WPB + (threadIdx.x >> 6);
    if (wave >= M) return;
    int lane = threadIdx.x & 63;
    const int* r = info + (size_t)wave * 4;
    int eid = r[0], start = r[2], len = r[3] - r[2];
    if (len <= 0) {
        if (lane == 0) atomicAdd(cnt + eid, 1.0f);
        return;
    }
    const float4* base = reinterpret_cast<const float4*>(enc)
                         + (size_t)start * (DDIM / 4) + lane;
    float4 acc = make_float4(0.f, 0.f, 0.f, 0.f);
    for (int i = 0; i < len; ++i) {
        float4 v = base[(size_t)i * (DDIM / 4)];
        acc.x += v.x; acc.y += v.y; acc.z += v.z; acc.w += v.w;
    }
    float inv = 1.0f / (float)len;
    float* dst = ent_sum + (size_t)eid * DDIM + lane * 4;
    atomicAdd(dst + 0, acc.x * inv);
    atomicAdd(dst + 1, acc.y * inv);
    atomicAdd(dst + 2, acc.z * inv);
    atomicAdd(dst + 3, acc.w * inv);
    if (lane == 0) atomicAdd(cnt + eid, 1.0f);
}

__global__ void finalize_kernel(float* __restrict__ out,
                                const float* __restrict__ cnt, int n) {
    int t = blockIdx.x * blockDim.x + threadIdx.x;
    if (t >= n) return;
    out[t] = out[t] / fmaxf(cnt[t >> 8], 1.0f);
}

extern "C" void kernel_launch(void* const* d_in, const int* in_sizes, int n_in,
                              void* d_out, int out_size, void* d_ws, size_t ws_size,
                              hipStream_t stream) {
    const float* enc  = (const float*)d_in[0];
    const int*   info = (const int*)d_in[1];   // int64 in source, but JAX x64 off -> int32

    int M = in_sizes[1] / 4;
    int E = out_size / DDIM;
    float* out = (float*)d_out;

    // bucket rows padded to 256 B (32 int2) for aligned header reads
    int strideI2 = (M + 31) & ~31;
    size_t cursor_bytes = ((size_t)E * sizeof(int) + 255) & ~(size_t)255;
    size_t need = cursor_bytes + (size_t)E * (size_t)strideI2 * sizeof(int2);

    if (ws_size >= need) {
        int*  cursor = (int*)d_ws;
        int2* bucket = (int2*)((char*)d_ws + cursor_bytes);

        hipMemsetAsync(cursor, 0, (size_t)E * sizeof(int), stream);
        scatter_kernel<<<(M + 255) / 256, 256, 0, stream>>>(
            info, cursor, bucket, M, strideI2);
        int gwaves = E * HALVES;
        int blocks = (gwaves + WPB - 1) / WPB;
        entity_kernel<<<blocks, 64 * WPB, 0, stream>>>(
            enc, cursor, bucket, out, strideI2, E);
    } else {
        float* cnt = (float*)d_ws;
        hipMemsetAsync(d_out, 0, (size_t)out_size * sizeof(float), stream);
        hipMemsetAsync(cnt, 0, (size_t)E * sizeof(float), stream);
        int blocks = (M + WPB - 1) / WPB;
        mention_accum_kernel<<<blocks, 64 * WPB, 0, stream>>>(enc, info, out, cnt, M);
        finalize_kernel<<<(out_size + 255) / 256, 256, 0, stream>>>(out, cnt, out_size);
    }
}